// Round 7
// baseline (263.846 us; speedup 1.0000x reference)
//
#include <hip/hip_runtime.h>
#include <hip/hip_bf16.h>

// Problem constants (from reference)
#define GG   8
#define NN   10000
#define EE   160000       // = 625 * 256 exactly
#define DIN  300
#define KP1  320          // DIN padded to mult of 32
#define DH   256
#define DOUT 128
#define MTOT 80000        // G*N rows = 625 * 128 exactly
#define LN_EPS 1e-5f

typedef short bf16x8 __attribute__((ext_vector_type(8)));
typedef float f32x4  __attribute__((ext_vector_type(4)));
typedef ushort u16x8 __attribute__((ext_vector_type(8)));

__device__ inline float bf2f(ushort u) {
    union { unsigned int i; float f; } x;
    x.i = ((unsigned int)u) << 16;
    return x.f;
}
__device__ inline ushort f2b(float f) {
    union { float f; unsigned int u; } x;
    x.f = f;
    unsigned int u = x.u;
    return (ushort)((u + 0x7fffu + ((u >> 16) & 1u)) >> 16);  // RNE (finite values)
}
__device__ inline short bcvt(float f) {
    __hip_bfloat16 h = __float2bfloat16(f);   // RNE; compiler emits v_cvt
    return *reinterpret_cast<short*>(&h);
}

// ---------------------------------------------------------------------------
// k_util: zero cnt + cast W1 -> w1t [256][320] + cast W2 -> w2t [128][256]
// ---------------------------------------------------------------------------
__global__ __launch_bounds__(256) void k_util(const float* __restrict__ W1,
                                              const float* __restrict__ W2,
                                              ushort* __restrict__ w1t,
                                              ushort* __restrict__ w2t,
                                              int* __restrict__ cnt) {
    int i = blockIdx.x * blockDim.x + threadIdx.x;
    if (i < GG * NN) cnt[i] = 0;
    if (i < DH * KP1) {
        int n = i / KP1, k = i % KP1;
        w1t[i] = (k < DIN) ? f2b(W1[(size_t)k * DH + n]) : 0;
    }
    if (i < DOUT * DH) {
        int n = i / DH, k = i % DH;
        w2t[i] = f2b(W2[(size_t)k * DOUT + n]);
    }
}

// ---------------------------------------------------------------------------
// CSR build kernels
// ---------------------------------------------------------------------------
__global__ __launch_bounds__(256) void k_count(const int* __restrict__ ei,
                                               int* __restrict__ cnt,
                                               int* __restrict__ slot) {
    int bid = blockIdx.x;
    int g = bid & 7;
    int e = (bid >> 3) * 256 + threadIdx.x;       // e < EE exactly
    int dst = ei[(size_t)g * 2 * EE + EE + e];
    slot[(size_t)g * EE + e] = atomicAdd(&cnt[g * NN + dst], 1);
}

__global__ void k_scan(const int* __restrict__ cnt, int* __restrict__ rowptr,
                       float* __restrict__ dinv) {
    int g = blockIdx.x;
    int t = threadIdx.x;                // 256 threads
    const int per = (NN + 255) / 256;   // 40
    __shared__ int sums[256];
    __shared__ int offs[257];
    int base = t * per;
    int s = 0;
    for (int i = 0; i < per; i++) {
        int n = base + i;
        if (n < NN) s += cnt[g * NN + n];
    }
    sums[t] = s;
    __syncthreads();
    if (t == 0) {
        int acc = 0;
        for (int i = 0; i < 256; i++) { offs[i] = acc; acc += sums[i]; }
        offs[256] = acc;
    }
    __syncthreads();
    int run = offs[t];
    for (int i = 0; i < per; i++) {
        int n = base + i;
        if (n < NN) {
            int c = cnt[g * NN + n];
            rowptr[g * (NN + 1) + n] = run;
            dinv[g * NN + n] = 1.0f / sqrtf(1.0f + (float)c);
            run += c;
        }
    }
    if (t == 255) rowptr[g * (NN + 1) + NN] = offs[256];
}

__global__ __launch_bounds__(256) void k_fill(const int* __restrict__ ei,
                                              const int* __restrict__ rowptr,
                                              const int* __restrict__ slot,
                                              const float* __restrict__ dinv,
                                              int2* __restrict__ edges) {
    int bid = blockIdx.x;
    int g = bid & 7;
    int e = (bid >> 3) * 256 + threadIdx.x;
    int src = ei[(size_t)g * 2 * EE + e];
    int dst = ei[(size_t)g * 2 * EE + EE + e];
    int pos = rowptr[g * (NN + 1) + dst] + slot[(size_t)g * EE + e];
    float coef = dinv[g * NN + src] * dinv[g * NN + dst];
    int2 rec;
    rec.x = src;
    rec.y = __float_as_int(coef);
    edges[(size_t)g * EE + pos] = rec;
}

// ---------------------------------------------------------------------------
// GEMM1:  C[80000,256] = bf16(x[80000,300]) @ W1  (fused fp32->bf16 cast)
// A-read-once structure (R6, verified): grid 625 x {128 rows, 8 waves x 16}.
// Lane holds its row's whole K-slice in regs; B in 4 col-quarters,
// double-buffered LDS (__syncthreads pattern, verified).
// NEW: vectorized C epilogue via per-wave LDS transpose.  Old epilogue was
// 64 scalar 2-byte stores/lane -> 32B write bursts; across 3 structures the
// kernel sat at ~66us with all pipes idle = effective-BW floor.  Transpose
// (XOR-chunk swizzled, bijective) lets 8 consecutive lanes store u16x8 =
// 128B bursts, 8x fewer store instructions.  One extra __syncthreads
// (full-drain semantics, race-free) before reusing Bs as scratch.
// ---------------------------------------------------------------------------
__global__ __launch_bounds__(512) void k_gemm1(const float* __restrict__ x,
                                               const ushort* __restrict__ Bt,
                                               ushort* __restrict__ C) {
    __shared__ ushort Bs[2][64 * 320];   // 2 x 40 KB (also epilogue scratch)
    const int tid = threadIdx.x;
    const int lane = tid & 63;
    const int w = tid >> 6;              // 0..7
    const int fr = lane & 15;            // row within wave tile
    const int hi = lane >> 4;            // 0..3, k-subchunk
    const int row = blockIdx.x * 128 + w * 16 + fr;
    const float* xr = x + (size_t)row * DIN;

    // ---- A: whole K-slice of this lane's row -> regs (cvt once) ----
    bf16x8 a[10];
#pragma unroll
    for (int kk = 0; kk < 10; kk++) {
        const int kb = kk * 32 + hi * 8;
        f32x4 p = *(const f32x4*)(xr + min(kb, DIN - 4));
        f32x4 q = *(const f32x4*)(xr + min(kb + 4, DIN - 4));
        a[kk][0] = bcvt(p[0]); a[kk][1] = bcvt(p[1]);
        a[kk][2] = bcvt(p[2]); a[kk][3] = bcvt(p[3]);
        a[kk][4] = bcvt(q[0]); a[kk][5] = bcvt(q[1]);
        a[kk][6] = bcvt(q[2]); a[kk][7] = bcvt(q[3]);
    }

    // stage one 64-col quarter of B: 64 rows x 40 chunks (u16x8), XOR'd dest
    auto stageQ = [&](int q, int buf) {
        for (int idx = tid; idx < 64 * 40; idx += 512) {
            const int r = idx / 40;
            const int c = idx - r * 40;
            const int cs = (c & ~7) | ((c & 7) ^ (r & 7));
            *(u16x8*)&Bs[buf][r * 320 + cs * 8] =
                *(const u16x8*)&Bt[(size_t)(q * 64 + r) * KP1 + c * 8];
        }
    };

    f32x4 acc[4][4];
#pragma unroll
    for (int q = 0; q < 4; q++)
#pragma unroll
        for (int j = 0; j < 4; j++) acc[q][j] = (f32x4){0.f, 0.f, 0.f, 0.f};

    stageQ(0, 0);
    __syncthreads();
#pragma unroll
    for (int q = 0; q < 4; q++) {
        const int buf = q & 1;
        if (q < 3) stageQ(q + 1, buf ^ 1);
#pragma unroll
        for (int kk = 0; kk < 10; kk++) {
            const int cb = kk * 4 + hi;            // global k-chunk index
#pragma unroll
            for (int j = 0; j < 4; j++) {
                const int r = j * 16 + fr;
                const int cs = (cb & ~7) | ((cb & 7) ^ (r & 7));
                bf16x8 bv = *(const bf16x8*)&Bs[buf][r * 320 + cs * 8];
                acc[q][j] = __builtin_amdgcn_mfma_f32_16x16x32_bf16(a[kk], bv,
                                                                    acc[q][j], 0, 0, 0);
            }
        }
        if (q < 3) __syncthreads();
    }

    // ---- vectorized epilogue: per-wave LDS transpose, 128B-burst stores ----
    __syncthreads();                          // all reads of Bs done
    ushort* tb = &Bs[0][0] + w * 4096;        // wave's private 16x256 tile (8KB)
#pragma unroll
    for (int q = 0; q < 4; q++)
#pragma unroll
        for (int j = 0; j < 4; j++) {
            const int chunk = q * 8 + j * 2 + (fr >> 3);
            const int lowc = fr & 7;
#pragma unroll
            for (int qq = 0; qq < 4; qq++) {
                const int rloc = hi * 4 + qq;
                const int sc = (chunk & ~7) | ((chunk & 7) ^ (rloc & 7));
                tb[rloc * 256 + sc * 8 + lowc] = f2b(acc[q][j][qq]);
            }
        }
    // same-wave write->read: compiler inserts lgkmcnt wait; no barrier needed
#pragma unroll
    for (int rr = 0; rr < 2; rr++)
#pragma unroll
        for (int i = 0; i < 4; i++) {
            const int rloc = (lane >> 3) + rr * 8;
            const int c = (lane & 7) + i * 8;
            const int sc = (c & ~7) | ((c & 7) ^ (rloc & 7));
            u16x8 v = *(const u16x8*)&tb[rloc * 256 + sc * 8];
            const int rowg = blockIdx.x * 128 + w * 16 + rloc;
            *(u16x8*)&C[(size_t)rowg * DH + c * 8] = v;
        }
}

// ---------------------------------------------------------------------------
// GEMM2: C[80000,128] = A[80000,256](bf16) @ w2t[128,256]^T
// Whole B in LDS (64 KB), stage once, one barrier, reg+LDS compute.
// NEW: same vectorized transpose epilogue (was 32 scalar stores/lane).
// ---------------------------------------------------------------------------
__global__ __launch_bounds__(512) void k_gemm2(const ushort* __restrict__ A,
                                               const ushort* __restrict__ Bt,
                                               ushort* __restrict__ C) {
    __shared__ ushort Bs[128 * 256];     // 64 KB (also epilogue scratch)
    const int tid = threadIdx.x;
    const int lane = tid & 63;
    const int w = tid >> 6;
    const int fr = lane & 15;
    const int hi = lane >> 4;
    const int row = blockIdx.x * 128 + w * 16 + fr;
    const ushort* ar = A + (size_t)row * DH;

    // A K-slice -> regs
    bf16x8 a[8];
#pragma unroll
    for (int kk = 0; kk < 8; kk++)
        a[kk] = *(const bf16x8*)(ar + kk * 32 + hi * 8);

    // stage whole B: 128 rows x 32 chunks, XOR'd dest
    for (int idx = tid; idx < 128 * 32; idx += 512) {
        const int r = idx >> 5;
        const int c = idx & 31;
        const int cs = (c & ~7) | ((c & 7) ^ (r & 7));
        *(u16x8*)&Bs[r * 256 + cs * 8] =
            *(const u16x8*)&Bt[(size_t)r * DH + c * 8];
    }
    __syncthreads();

    f32x4 acc[8];
#pragma unroll
    for (int j = 0; j < 8; j++) acc[j] = (f32x4){0.f, 0.f, 0.f, 0.f};

#pragma unroll
    for (int kk = 0; kk < 8; kk++) {
        const int cb = kk * 4 + hi;
#pragma unroll
        for (int j = 0; j < 8; j++) {
            const int r = j * 16 + fr;
            const int cs = (cb & ~7) | ((cb & 7) ^ (r & 7));
            bf16x8 bv = *(const bf16x8*)&Bs[r * 256 + cs * 8];
            acc[j] = __builtin_amdgcn_mfma_f32_16x16x32_bf16(a[kk], bv,
                                                             acc[j], 0, 0, 0);
        }
    }

    // ---- vectorized epilogue: per-wave LDS transpose ----
    __syncthreads();                     // all reads of Bs done
    ushort* tb = Bs + w * 2048;          // wave's private 16x128 tile (4KB)
#pragma unroll
    for (int j = 0; j < 8; j++) {
        const int chunk = j * 2 + (fr >> 3);
        const int lowc = fr & 7;
#pragma unroll
        for (int qq = 0; qq < 4; qq++) {
            const int rloc = hi * 4 + qq;
            const int sc = (chunk & ~7) | ((chunk & 7) ^ (rloc & 7));
            tb[rloc * 128 + sc * 8 + lowc] = f2b(acc[j][qq]);
        }
    }
#pragma unroll
    for (int rr = 0; rr < 2; rr++)
#pragma unroll
        for (int i = 0; i < 2; i++) {
            const int rloc = (lane >> 3) + rr * 8;
            const int c = (lane & 7) + i * 8;
            const int sc = (c & ~7) | ((c & 7) ^ (rloc & 7));
            u16x8 v = *(const u16x8*)&tb[rloc * 128 + sc * 8];
            const int rowg = blockIdx.x * 128 + w * 16 + rloc;
            *(u16x8*)&C[(size_t)rowg * DOUT + c * 8] = v;
        }
}

// ---------------------------------------------------------------------------
// Fused aggregation + bias (+ReLU) + LayerNorm.  ONE LANE-GROUP PER NODE.
// NEW: feature-width F is a template param.  conv1 (D=256) uses F=16 ->
// GL=16 lanes/node, 4 nodes/wave (was 2): doubles independent gather
// streams per wave (latency overlap), halves serial depth per node.
// conv2 (D=128) unchanged at F=8 (GL=16, 4 nodes/wave).
// All inner loops statically unrolled (no runtime-indexed vector arrays).
// ---------------------------------------------------------------------------
template <int D, int F, bool RELU, typename OutT>
__global__ __launch_bounds__(256) void k_agg(const ushort* __restrict__ h,
                                             const int* __restrict__ rowptr,
                                             const int2* __restrict__ edges,
                                             const float* __restrict__ dinv,
                                             const float* __restrict__ bias,
                                             const float* __restrict__ gam,
                                             const float* __restrict__ bet,
                                             OutT* __restrict__ out) {
    constexpr int NV = F / 8;          // u16x8 gathers per lane per record
    constexpr int GL = D / F;          // lanes per node group
    constexpr int NPW = 64 / GL;       // nodes per wave
    __shared__ int2 s_rec[4][64];      // per-wave record slots (2KB)
    const int tid = threadIdx.x;
    const int lane = tid & 63;
    const int wv = tid >> 6;
    const int grp = lane / GL;         // node slot within wave
    const int gl = lane & (GL - 1);    // lane within group
    const int fb = gl * F;             // feature base
    const int g = blockIdx.x & 7;      // graph -> XCD affinity
    const int n = (blockIdx.x >> 3) * (4 * NPW) + wv * NPW + grp;
    const ushort* hg = h + (size_t)g * NN * D;
    const int2* eg = edges + (size_t)g * EE;
    const int r0 = rowptr[g * (NN + 1) + n];
    const int r1 = rowptr[g * (NN + 1) + n + 1];
    const float dn = dinv[g * NN + n];
    int2* srw = &s_rec[wv][grp * GL];  // group's private slot region

    float acc[F];
#pragma unroll
    for (int i = 0; i < F; i++) acc[i] = 0.f;

    for (int base = r0; base < r1; base += GL) {
        const int c = min(GL, r1 - base);
        int2 rec;
        rec.x = 0;
        rec.y = 0;
        if (gl < c) rec = eg[base + gl];
        srw[gl] = rec;
        const int cpad = (c + 3) & ~3;
        for (int j = 0; j < cpad; j += 4) {
            const int4 ra = *(const int4*)&srw[j];      // records j, j+1
            const int4 rb = *(const int4*)&srw[j + 2];  // records j+2, j+3
            const ushort* hp0 = &hg[(size_t)ra.x * D + fb];
            const ushort* hp1 = &hg[(size_t)ra.z * D + fb];
            const ushort* hp2 = &hg[(size_t)rb.x * D + fb];
            const ushort* hp3 = &hg[(size_t)rb.z * D + fb];
            const float w0 = __int_as_float(ra.y);
            const float w1 = __int_as_float(ra.w);
            const float w2 = __int_as_float(rb.y);
            const float w3 = __int_as_float(rb.w);
#pragma unroll
            for (int v = 0; v < NV; v++) {
                u16x8 v0 = *(const u16x8*)(hp0 + v * 8);
                u16x8 v1 = *(const u16x8*)(hp1 + v * 8);
                u16x8 v2 = *(const u16x8*)(hp2 + v * 8);
                u16x8 v3 = *(const u16x8*)(hp3 + v * 8);
#pragma unroll
                for (int i = 0; i < 8; i++) acc[v * 8 + i] = fmaf(bf2f(v0[i]), w0, acc[v * 8 + i]);
#pragma unroll
                for (int i = 0; i < 8; i++) acc[v * 8 + i] = fmaf(bf2f(v1[i]), w1, acc[v * 8 + i]);
#pragma unroll
                for (int i = 0; i < 8; i++) acc[v * 8 + i] = fmaf(bf2f(v2[i]), w2, acc[v * 8 + i]);
#pragma unroll
                for (int i = 0; i < 8; i++) acc[v * 8 + i] = fmaf(bf2f(v3[i]), w3, acc[v * 8 + i]);
            }
        }
    }

    {   // self-loop + bias (+relu)
        const float ws = dn * dn;
        const ushort* hp = &hg[(size_t)n * D + fb];
#pragma unroll
        for (int v = 0; v < NV; v++) {
            u16x8 vv = *(const u16x8*)(hp + v * 8);
#pragma unroll
            for (int i = 0; i < 8; i++) {
                const int ii = v * 8 + i;
                acc[ii] = fmaf(bf2f(vv[i]), ws, acc[ii]);
                acc[ii] += bias[fb + ii];
                if (RELU) acc[ii] = fmaxf(acc[ii], 0.f);
            }
        }
    }
    float s1 = 0.f, s2 = 0.f;
#pragma unroll
    for (int i = 0; i < F; i++) { s1 += acc[i]; s2 += acc[i] * acc[i]; }
#pragma unroll
    for (int o = GL / 2; o > 0; o >>= 1) {
        s1 += __shfl_xor(s1, o);
        s2 += __shfl_xor(s2, o);
    }
    const float mu = s1 / D;
    const float rs = rsqrtf(s2 / D - mu * mu + LN_EPS);

    if constexpr (sizeof(OutT) == 2) {
#pragma unroll
        for (int v = 0; v < NV; v++) {
            u16x8 o;
#pragma unroll
            for (int i = 0; i < 8; i++) {
                const int ii = v * 8 + i;
                o[i] = f2b((acc[ii] - mu) * rs * gam[fb + ii] + bet[fb + ii]);
            }
            *(u16x8*)&((ushort*)out)[((size_t)g * NN + n) * D + fb + v * 8] = o;
        }
    } else {
        float* op = &((float*)out)[((size_t)g * NN + n) * D + fb];
#pragma unroll
        for (int c4 = 0; c4 < F / 4; c4++) {
            float4 o;
            o.x = (acc[c4 * 4 + 0] - mu) * rs * gam[fb + c4 * 4 + 0] + bet[fb + c4 * 4 + 0];
            o.y = (acc[c4 * 4 + 1] - mu) * rs * gam[fb + c4 * 4 + 1] + bet[fb + c4 * 4 + 1];
            o.z = (acc[c4 * 4 + 2] - mu) * rs * gam[fb + c4 * 4 + 2] + bet[fb + c4 * 4 + 2];
            o.w = (acc[c4 * 4 + 3] - mu) * rs * gam[fb + c4 * 4 + 3] + bet[fb + c4 * 4 + 3];
            *(float4*)&op[c4 * 4] = o;
        }
    }
}

// ---------------------------------------------------------------------------
extern "C" void kernel_launch(void* const* d_in, const int* in_sizes, int n_in,
                              void* d_out, int out_size, void* d_ws, size_t ws_size,
                              hipStream_t stream) {
    const float* x   = (const float*)d_in[0];  // [G,N,300]
    const int*   ei  = (const int*)d_in[1];    // [G,2,E]
    const float* W1  = (const float*)d_in[2];  // [300,256]
    const float* b1  = (const float*)d_in[3];
    const float* g1  = (const float*)d_in[4];
    const float* be1 = (const float*)d_in[5];
    const float* W2  = (const float*)d_in[6];  // [256,128]
    const float* b2  = (const float*)d_in[7];
    const float* g2  = (const float*)d_in[8];
    const float* be2 = (const float*)d_in[9];
    float* out = (float*)d_out;                // [G,N,128]

    // workspace layout (all 16B-aligned)
    char* w = (char*)d_ws;
    ushort* w1t  = (ushort*)w;                        w += (size_t)DH * KP1 * 2;
    ushort* w2t  = (ushort*)w;                        w += (size_t)DOUT * DH * 2;
    ushort* h1b  = (ushort*)w;                        w += (size_t)MTOT * DH * 2;     // 41MB
    ushort* out1 = (ushort*)w;                        w += (size_t)MTOT * DH * 2;     // 41MB
    int*   cnt    = (int*)w;                          w += (size_t)GG * NN * 4;
    int*   rowptr = (int*)w;                          w += (size_t)GG * (NN + 1) * 4 + 224; // pad to 16B
    int*   slot   = (int*)w;                          w += (size_t)GG * EE * 4;       // 5.1MB
    float* dinv   = (float*)w;                        w += (size_t)GG * NN * 4;
    int2*  edges  = (int2*)w;                         /* G*E*8 = 10.2MB */
    ushort* h2b = h1b;

    // 1. util: zero cnt + cast W1/W2 (one launch)
    k_util<<<dim3((DH * KP1 + 255) / 256), dim3(256), 0, stream>>>(W1, W2, w1t, w2t, cnt);

    // 2. build CSR (atomic slot assign -> scan -> atomic-free fill w/ fat records)
    k_count<<<dim3((EE / 256) * GG), dim3(256), 0, stream>>>(ei, cnt, slot);
    k_scan<<<dim3(GG), dim3(256), 0, stream>>>(cnt, rowptr, dinv);
    k_fill<<<dim3((EE / 256) * GG), dim3(256), 0, stream>>>(ei, rowptr, slot, dinv, edges);

    // 3. h1 = bf16(x) @ W1  (A-read-once, B quarter-dbuf LDS, vec epilogue)
    k_gemm1<<<dim3(MTOT / 128), dim3(512), 0, stream>>>(x, w1t, h1b);

    // 4. conv1 aggregate + bias + relu + LN -> out1 (bf16): F=16, 16 nodes/block
    k_agg<DH, 16, true, ushort><<<dim3((NN / 16) * GG), dim3(256), 0, stream>>>(
        h1b, rowptr, edges, dinv, b1, g1, be1, out1);

    // 5. h2 = out1 @ W2  (B fully LDS-resident, vec epilogue)
    k_gemm2<<<dim3(MTOT / 128), dim3(512), 0, stream>>>(out1, w2t, h2b);

    // 6. conv2 aggregate + bias + LN -> d_out (fp32): F=8, 16 nodes/block
    k_agg<DOUT, 8, false, float><<<dim3((NN / 16) * GG), dim3(256), 0, stream>>>(
        h2b, rowptr, edges, dinv, b2, g2, be2, out);
}

// Round 8
// 247.475 us; speedup vs baseline: 1.0662x; 1.0662x over previous
//
#include <hip/hip_runtime.h>
#include <hip/hip_bf16.h>

// Problem constants (from reference)
#define GG   8
#define NN   10000
#define EE   160000       // = 625 * 256 exactly
#define DIN  300
#define KP1  320          // DIN padded to mult of 32
#define DH   256
#define DOUT 128
#define MTOT 80000        // G*N rows
#define LN_EPS 1e-5f

typedef short bf16x8 __attribute__((ext_vector_type(8)));
typedef float f32x4  __attribute__((ext_vector_type(4)));
typedef ushort u16x8 __attribute__((ext_vector_type(8)));

__device__ inline float bf2f(ushort u) {
    union { unsigned int i; float f; } x;
    x.i = ((unsigned int)u) << 16;
    return x.f;
}
__device__ inline ushort f2b(float f) {
    union { float f; unsigned int u; } x;
    x.f = f;
    unsigned int u = x.u;
    return (ushort)((u + 0x7fffu + ((u >> 16) & 1u)) >> 16);  // RNE (finite values)
}
__device__ inline short bcvt(float f) {
    __hip_bfloat16 h = __float2bfloat16(f);   // RNE; compiler emits v_cvt
    return *reinterpret_cast<short*>(&h);
}

// ---------------------------------------------------------------------------
// k_util: zero cnt + cast W1 -> w1t [256][320] + cast W2 -> w2t [128][256]
// ---------------------------------------------------------------------------
__global__ __launch_bounds__(256) void k_util(const float* __restrict__ W1,
                                              const float* __restrict__ W2,
                                              ushort* __restrict__ w1t,
                                              ushort* __restrict__ w2t,
                                              int* __restrict__ cnt) {
    int i = blockIdx.x * blockDim.x + threadIdx.x;
    if (i < GG * NN) cnt[i] = 0;
    if (i < DH * KP1) {
        int n = i / KP1, k = i % KP1;
        w1t[i] = (k < DIN) ? f2b(W1[(size_t)k * DH + n]) : 0;
    }
    if (i < DOUT * DH) {
        int n = i / DH, k = i % DH;
        w2t[i] = f2b(W2[(size_t)k * DOUT + n]);
    }
}

// ---------------------------------------------------------------------------
// CSR build kernels
// ---------------------------------------------------------------------------
__global__ __launch_bounds__(256) void k_count(const int* __restrict__ ei,
                                               int* __restrict__ cnt,
                                               int* __restrict__ slot) {
    int bid = blockIdx.x;
    int g = bid & 7;
    int e = (bid >> 3) * 256 + threadIdx.x;       // e < EE exactly
    int dst = ei[(size_t)g * 2 * EE + EE + e];
    slot[(size_t)g * EE + e] = atomicAdd(&cnt[g * NN + dst], 1);
}

__global__ void k_scan(const int* __restrict__ cnt, int* __restrict__ rowptr,
                       float* __restrict__ dinv) {
    int g = blockIdx.x;
    int t = threadIdx.x;                // 256 threads
    const int per = (NN + 255) / 256;   // 40
    __shared__ int sums[256];
    __shared__ int offs[257];
    int base = t * per;
    int s = 0;
    for (int i = 0; i < per; i++) {
        int n = base + i;
        if (n < NN) s += cnt[g * NN + n];
    }
    sums[t] = s;
    __syncthreads();
    if (t == 0) {
        int acc = 0;
        for (int i = 0; i < 256; i++) { offs[i] = acc; acc += sums[i]; }
        offs[256] = acc;
    }
    __syncthreads();
    int run = offs[t];
    for (int i = 0; i < per; i++) {
        int n = base + i;
        if (n < NN) {
            int c = cnt[g * NN + n];
            rowptr[g * (NN + 1) + n] = run;
            dinv[g * NN + n] = 1.0f / sqrtf(1.0f + (float)c);
            run += c;
        }
    }
    if (t == 255) rowptr[g * (NN + 1) + NN] = offs[256];
}

__global__ __launch_bounds__(256) void k_fill(const int* __restrict__ ei,
                                              const int* __restrict__ rowptr,
                                              const int* __restrict__ slot,
                                              const float* __restrict__ dinv,
                                              int2* __restrict__ edges) {
    int bid = blockIdx.x;
    int g = bid & 7;
    int e = (bid >> 3) * 256 + threadIdx.x;
    int src = ei[(size_t)g * 2 * EE + e];
    int dst = ei[(size_t)g * 2 * EE + EE + e];
    int pos = rowptr[g * (NN + 1) + dst] + slot[(size_t)g * EE + e];
    float coef = dinv[g * NN + src] * dinv[g * NN + dst];
    int2 rec;
    rec.x = src;
    rec.y = __float_as_int(coef);
    edges[(size_t)g * EE + pos] = rec;
}

// ---------------------------------------------------------------------------
// GEMM1 (round-4 verified, 62.6us): C[80000,256] = bf16(x) @ W1.
// TILE 64x256, 256 threads (4 waves x 64 cols).  Two __syncthreads per
// K-step, reg-staged A + ds_write, B via global_load_lds, Bs XOR(row&3)
// swizzle.  As padded stride 36 floats.
// ---------------------------------------------------------------------------
__global__ __launch_bounds__(256) void k_gemm1(const float* __restrict__ x,
                                               const ushort* __restrict__ Bt,
                                               ushort* __restrict__ C) {
    __shared__ float  As[64 * 36];     // 9 KB, padded stride 36
    __shared__ ushort Bs[256 * 32];    // 16 KB
    const int tid = threadIdx.x;
    const int lane = tid & 63;
    const int w = tid >> 6;            // 0..3
    const int wn = w;                  // N dir, 64 cols each (wm = 0)
    const int m0 = blockIdx.x * 64;

    const int fr = lane & 15;
    const int fk = (lane >> 4) * 8;              // k offset (elements)
    const int fksB = fk ^ ((fr & 3) * 8);        // swizzled B read slot

    // A staging: thread -> row = tid>>2 (0..63), colf = (tid&3)*8 floats
    const int arow = tid >> 2;
    const int acol = (tid & 3) * 8;
    const float* xr = x + (size_t)(m0 + arow) * DIN;

    // B staging: round r: global row = r*64 + tid>>2; source col pre-swizzled
    const int brow4 = (tid >> 2) & 3;                 // row&3 (r*64 == 0 mod 4)
    const int bcol = ((tid & 3) ^ brow4) * 8;         // slot c holds chunk c^(row&3)

    f32x4 acc[4][4];
#pragma unroll
    for (int i = 0; i < 4; i++)
#pragma unroll
        for (int j = 0; j < 4; j++) acc[i][j] = (f32x4){0.f, 0.f, 0.f, 0.f};

    // prologue: prefetch A regs for k0 = 0
    float4 a0 = *(const float4*)(xr + min(acol, DIN - 4));
    float4 a1 = *(const float4*)(xr + min(acol + 4, DIN - 4));

    for (int k0 = 0; k0 < KP1; k0 += 32) {
        // write staged A regs (prev-iter compute done at loop-end barrier)
        *(float4*)&As[arow * 36 + acol] = a0;
        *(float4*)&As[arow * 36 + acol + 4] = a1;
        // B: async global->LDS (wave-uniform dest base!)
#pragma unroll
        for (int r = 0; r < 4; r++) {
            const ushort* gb = &Bt[(size_t)(r * 64 + (tid >> 2)) * KP1 + k0 + bcol];
            __builtin_amdgcn_global_load_lds(
                (const __attribute__((address_space(1))) void*)gb,
                (__attribute__((address_space(3))) void*)&Bs[(r * 64 + w * 16) * 32],
                16, 0, 0);
        }
        // prefetch next-iter A regs (hides HBM latency under MFMA phase)
        {
            const int kn = k0 + 32;
            a0 = *(const float4*)(xr + min(kn + acol, DIN - 4));
            a1 = *(const float4*)(xr + min(kn + acol + 4, DIN - 4));
        }
        __syncthreads();
        bf16x8 af[4], bfv[4];
#pragma unroll
        for (int i = 0; i < 4; i++) {
            const float* ap = &As[(i * 16 + fr) * 36 + fk];
            f32x4 p = *(const f32x4*)ap;
            f32x4 q = *(const f32x4*)(ap + 4);
            af[i][0] = bcvt(p[0]); af[i][1] = bcvt(p[1]);
            af[i][2] = bcvt(p[2]); af[i][3] = bcvt(p[3]);
            af[i][4] = bcvt(q[0]); af[i][5] = bcvt(q[1]);
            af[i][6] = bcvt(q[2]); af[i][7] = bcvt(q[3]);
            bfv[i] = *(const bf16x8*)&Bs[(wn * 64 + i * 16 + fr) * 32 + fksB];
        }
#pragma unroll
        for (int i = 0; i < 4; i++)
#pragma unroll
            for (int j = 0; j < 4; j++)
                acc[i][j] = __builtin_amdgcn_mfma_f32_16x16x32_bf16(af[i], bfv[j],
                                                                    acc[i][j], 0, 0, 0);
        __syncthreads();
    }

    // epilogue: C/D layout col=lane&15, row=(lane>>4)*4+q
#pragma unroll
    for (int i = 0; i < 4; i++) {
        int row0 = m0 + i * 16 + (lane >> 4) * 4;
#pragma unroll
        for (int j = 0; j < 4; j++) {
            int col = wn * 64 + j * 16 + fr;
#pragma unroll
            for (int q = 0; q < 4; q++) {
                C[(size_t)(row0 + q) * DH + col] = f2b(acc[i][j][q]);
            }
        }
    }
}

// ---------------------------------------------------------------------------
// FUSED conv1-aggregate + bias + ReLU + LN + (x @ W2) -> h2 (bf16).
// Phase 1 = verified k_agg F=8 path (GL=32 lanes/node, 2 nodes/wave), but
// with 8 waves (512 thr) so the block owns 16 nodes.  The LN'd bf16 row goes
// to LDS rows[16][256] (XOR-chunk swizzle, the verified gemm staging layout)
// instead of global out1 — saving out1's 41MB write + gemm2's 41MB read.
// Phase 2 (after ONE __syncthreads): per-wave 16x16 mini-GEMM vs w2t read
// straight from global (64KB, L2-hot): wave w computes cols w*16..+15 of all
// 16 node rows via 8 MFMAs, same fragment k-order as the old k_gemm2 ->
// bit-identical h2.  Output h2 MUST NOT alias h1 (other blocks still gather
// h1) — caller passes the spare out1 region.
// ---------------------------------------------------------------------------
__global__ __launch_bounds__(512) void k_agg_gemm(const ushort* __restrict__ h,
                                                  const int* __restrict__ rowptr,
                                                  const int2* __restrict__ edges,
                                                  const float* __restrict__ dinv,
                                                  const float* __restrict__ bias,
                                                  const float* __restrict__ gam,
                                                  const float* __restrict__ bet,
                                                  const ushort* __restrict__ w2t,
                                                  ushort* __restrict__ h2) {
    constexpr int F = 8, GL = 32, NPW = 2;     // verified conv1 geometry
    __shared__ int2 s_rec[8][64];              // per-wave record slots (4KB)
    __shared__ ushort rows[16 * 256];          // LN'd rows, swizzled (8KB)
    const int tid = threadIdx.x;
    const int lane = tid & 63;
    const int wv = tid >> 6;                   // 0..7
    const int grp = lane / GL;                 // 0..1
    const int gl = lane & (GL - 1);            // 0..31
    const int fb = gl * F;
    const int g = blockIdx.x & 7;              // graph -> XCD affinity
    const int nb = (blockIdx.x >> 3) * 16;     // block's node base
    const int node = wv * NPW + grp;           // 0..15
    const int n = nb + node;
    const ushort* hg = h + (size_t)g * NN * DH;
    const int2* eg = edges + (size_t)g * EE;
    const int r0 = rowptr[g * (NN + 1) + n];
    const int r1 = rowptr[g * (NN + 1) + n + 1];
    const float dn = dinv[g * NN + n];
    int2* srw = &s_rec[wv][grp * GL];

    float acc[F];
#pragma unroll
    for (int i = 0; i < F; i++) acc[i] = 0.f;

    for (int base = r0; base < r1; base += GL) {
        const int c = min(GL, r1 - base);
        int2 rec;
        rec.x = 0;
        rec.y = 0;
        if (gl < c) rec = eg[base + gl];
        srw[gl] = rec;
        const int cpad = (c + 3) & ~3;
        for (int j = 0; j < cpad; j += 4) {
            const int4 ra = *(const int4*)&srw[j];
            const int4 rb = *(const int4*)&srw[j + 2];
            u16x8 v0 = *(const u16x8*)&hg[(size_t)ra.x * DH + fb];
            u16x8 v1 = *(const u16x8*)&hg[(size_t)ra.z * DH + fb];
            u16x8 v2 = *(const u16x8*)&hg[(size_t)rb.x * DH + fb];
            u16x8 v3 = *(const u16x8*)&hg[(size_t)rb.z * DH + fb];
            const float w0 = __int_as_float(ra.y);
            const float w1 = __int_as_float(ra.w);
            const float w2 = __int_as_float(rb.y);
            const float w3 = __int_as_float(rb.w);
#pragma unroll
            for (int i = 0; i < F; i++) acc[i] = fmaf(bf2f(v0[i]), w0, acc[i]);
#pragma unroll
            for (int i = 0; i < F; i++) acc[i] = fmaf(bf2f(v1[i]), w1, acc[i]);
#pragma unroll
            for (int i = 0; i < F; i++) acc[i] = fmaf(bf2f(v2[i]), w2, acc[i]);
#pragma unroll
            for (int i = 0; i < F; i++) acc[i] = fmaf(bf2f(v3[i]), w3, acc[i]);
        }
    }

    {   // self-loop + bias + relu
        const float ws = dn * dn;
        u16x8 v = *(const u16x8*)&hg[(size_t)n * DH + fb];
#pragma unroll
        for (int i = 0; i < F; i++) {
            acc[i] = fmaf(bf2f(v[i]), ws, acc[i]);
            acc[i] += bias[fb + i];
            acc[i] = fmaxf(acc[i], 0.f);
        }
    }
    float s1 = 0.f, s2 = 0.f;
#pragma unroll
    for (int i = 0; i < F; i++) { s1 += acc[i]; s2 += acc[i] * acc[i]; }
#pragma unroll
    for (int o = GL / 2; o > 0; o >>= 1) {
        s1 += __shfl_xor(s1, o);
        s2 += __shfl_xor(s2, o);
    }
    const float mu = s1 / DH;
    const float rs = rsqrtf(s2 / DH - mu * mu + LN_EPS);

    {   // LN'd bf16 row -> LDS (chunk gl, XOR-swizzled slot; bijective/row)
        u16x8 o;
#pragma unroll
        for (int i = 0; i < F; i++)
            o[i] = f2b((acc[i] - mu) * rs * gam[fb + i] + bet[fb + i]);
        const int slot = (gl & ~7) | ((gl & 7) ^ (node & 7));
        *(u16x8*)&rows[node * 256 + slot * 8] = o;
    }
    __syncthreads();

    // ---- phase 2: h2[nb..nb+15][:] = rows @ w2t^T  (wave w: cols w*16..+15)
    const int fr = lane & 15;
    const int hi = lane >> 4;
    const ushort* w2row = w2t + (size_t)(wv * 16 + fr) * DH;
    f32x4 acc2 = (f32x4){0.f, 0.f, 0.f, 0.f};
#pragma unroll
    for (int kk = 0; kk < 8; kk++) {
        const int cb = kk * 4 + hi;                       // chunk 0..31
        const int slot = (cb & ~7) | ((cb & 7) ^ (fr & 7));
        bf16x8 av = *(const bf16x8*)&rows[fr * 256 + slot * 8];
        bf16x8 bv = *(const bf16x8*)(w2row + kk * 32 + hi * 8);
        acc2 = __builtin_amdgcn_mfma_f32_16x16x32_bf16(av, bv, acc2, 0, 0, 0);
    }
    // D layout: row = hi*4+q (node), col = fr
#pragma unroll
    for (int q = 0; q < 4; q++) {
        const int rowg = g * NN + nb + hi * 4 + q;
        h2[(size_t)rowg * DOUT + wv * 16 + fr] = f2b(acc2[q]);
    }
}

// ---------------------------------------------------------------------------
// Fused aggregation + bias + LayerNorm (conv2, round-4 verified template).
// ---------------------------------------------------------------------------
template <int D, bool RELU, typename OutT>
__global__ __launch_bounds__(256) void k_agg(const ushort* __restrict__ h,
                                             const int* __restrict__ rowptr,
                                             const int2* __restrict__ edges,
                                             const float* __restrict__ dinv,
                                             const float* __restrict__ bias,
                                             const float* __restrict__ gam,
                                             const float* __restrict__ bet,
                                             OutT* __restrict__ out) {
    constexpr int F = 8;               // features per lane (16B gathers)
    constexpr int GL = D / F;          // lanes per node group (32 / 16)
    constexpr int NPW = 64 / GL;       // nodes per wave (2 / 4)
    __shared__ int2 s_rec[4][64];      // per-wave record slots (2KB)
    const int tid = threadIdx.x;
    const int lane = tid & 63;
    const int wv = tid >> 6;
    const int grp = lane / GL;         // node slot within wave
    const int gl = lane & (GL - 1);    // lane within group
    const int fb = gl * F;             // feature base
    const int g = blockIdx.x & 7;      // graph -> XCD affinity
    const int n = (blockIdx.x >> 3) * (4 * NPW) + wv * NPW + grp;
    const ushort* hg = h + (size_t)g * NN * D;
    const int2* eg = edges + (size_t)g * EE;
    const int r0 = rowptr[g * (NN + 1) + n];
    const int r1 = rowptr[g * (NN + 1) + n + 1];
    const float dn = dinv[g * NN + n];
    int2* srw = &s_rec[wv][grp * GL];  // group's private slot region

    float acc[F];
#pragma unroll
    for (int i = 0; i < F; i++) acc[i] = 0.f;

    for (int base = r0; base < r1; base += GL) {
        const int c = min(GL, r1 - base);
        int2 rec;
        rec.x = 0;
        rec.y = 0;
        if (gl < c) rec = eg[base + gl];
        srw[gl] = rec;
        const int cpad = (c + 3) & ~3;
        for (int j = 0; j < cpad; j += 4) {
            const int4 ra = *(const int4*)&srw[j];      // records j, j+1
            const int4 rb = *(const int4*)&srw[j + 2];  // records j+2, j+3
            u16x8 v0 = *(const u16x8*)&hg[(size_t)ra.x * D + fb];
            u16x8 v1 = *(const u16x8*)&hg[(size_t)ra.z * D + fb];
            u16x8 v2 = *(const u16x8*)&hg[(size_t)rb.x * D + fb];
            u16x8 v3 = *(const u16x8*)&hg[(size_t)rb.z * D + fb];
            const float w0 = __int_as_float(ra.y);
            const float w1 = __int_as_float(ra.w);
            const float w2 = __int_as_float(rb.y);
            const float w3 = __int_as_float(rb.w);
#pragma unroll
            for (int i = 0; i < F; i++) acc[i] = fmaf(bf2f(v0[i]), w0, acc[i]);
#pragma unroll
            for (int i = 0; i < F; i++) acc[i] = fmaf(bf2f(v1[i]), w1, acc[i]);
#pragma unroll
            for (int i = 0; i < F; i++) acc[i] = fmaf(bf2f(v2[i]), w2, acc[i]);
#pragma unroll
            for (int i = 0; i < F; i++) acc[i] = fmaf(bf2f(v3[i]), w3, acc[i]);
        }
    }

    {
        const float ws = dn * dn;
        u16x8 v = *(const u16x8*)&hg[(size_t)n * D + fb];
#pragma unroll
        for (int i = 0; i < F; i++) {
            acc[i] = fmaf(bf2f(v[i]), ws, acc[i]);
            acc[i] += bias[fb + i];
            if (RELU) acc[i] = fmaxf(acc[i], 0.f);
        }
    }
    float s1 = 0.f, s2 = 0.f;
#pragma unroll
    for (int i = 0; i < F; i++) { s1 += acc[i]; s2 += acc[i] * acc[i]; }
#pragma unroll
    for (int o = GL / 2; o > 0; o >>= 1) {
        s1 += __shfl_xor(s1, o);
        s2 += __shfl_xor(s2, o);
    }
    const float mu = s1 / D;
    const float rs = rsqrtf(s2 / D - mu * mu + LN_EPS);

    if constexpr (sizeof(OutT) == 2) {
        u16x8 o;
#pragma unroll
        for (int i = 0; i < F; i++)
            o[i] = f2b((acc[i] - mu) * rs * gam[fb + i] + bet[fb + i]);
        *(u16x8*)&((ushort*)out)[((size_t)g * NN + n) * D + fb] = o;
    } else {
        float* op = &((float*)out)[((size_t)g * NN + n) * D + fb];
        float4 oa, ob;
        oa.x = (acc[0] - mu) * rs * gam[fb + 0] + bet[fb + 0];
        oa.y = (acc[1] - mu) * rs * gam[fb + 1] + bet[fb + 1];
        oa.z = (acc[2] - mu) * rs * gam[fb + 2] + bet[fb + 2];
        oa.w = (acc[3] - mu) * rs * gam[fb + 3] + bet[fb + 3];
        ob.x = (acc[4] - mu) * rs * gam[fb + 4] + bet[fb + 4];
        ob.y = (acc[5] - mu) * rs * gam[fb + 5] + bet[fb + 5];
        ob.z = (acc[6] - mu) * rs * gam[fb + 6] + bet[fb + 6];
        ob.w = (acc[7] - mu) * rs * gam[fb + 7] + bet[fb + 7];
        *(float4*)&op[0] = oa;
        *(float4*)&op[4] = ob;
    }
}

// ---------------------------------------------------------------------------
extern "C" void kernel_launch(void* const* d_in, const int* in_sizes, int n_in,
                              void* d_out, int out_size, void* d_ws, size_t ws_size,
                              hipStream_t stream) {
    const float* x   = (const float*)d_in[0];  // [G,N,300]
    const int*   ei  = (const int*)d_in[1];    // [G,2,E]
    const float* W1  = (const float*)d_in[2];  // [300,256]
    const float* b1  = (const float*)d_in[3];
    const float* g1  = (const float*)d_in[4];
    const float* be1 = (const float*)d_in[5];
    const float* W2  = (const float*)d_in[6];  // [256,128]
    const float* b2  = (const float*)d_in[7];
    const float* g2  = (const float*)d_in[8];
    const float* be2 = (const float*)d_in[9];
    float* out = (float*)d_out;                // [G,N,128]

    // workspace layout (all 16B-aligned)
    char* w = (char*)d_ws;
    ushort* w1t  = (ushort*)w;                        w += (size_t)DH * KP1 * 2;
    ushort* w2t  = (ushort*)w;                        w += (size_t)DOUT * DH * 2;
    ushort* h1b  = (ushort*)w;                        w += (size_t)MTOT * DH * 2;     // 41MB
    ushort* h2b  = (ushort*)w;                        w += (size_t)MTOT * DH * 2;     // spare region (h2: 20MB used)
    int*   cnt    = (int*)w;                          w += (size_t)GG * NN * 4;
    int*   rowptr = (int*)w;                          w += (size_t)GG * (NN + 1) * 4 + 224; // pad to 16B
    int*   slot   = (int*)w;                          w += (size_t)GG * EE * 4;       // 5.1MB
    float* dinv   = (float*)w;                        w += (size_t)GG * NN * 4;
    int2*  edges  = (int2*)w;                         /* G*E*8 = 10.2MB */

    // 1. util: zero cnt + cast W1/W2 (one launch)
    k_util<<<dim3((DH * KP1 + 255) / 256), dim3(256), 0, stream>>>(W1, W2, w1t, w2t, cnt);

    // 2. build CSR (atomic slot assign -> scan -> atomic-free fill w/ fat records)
    k_count<<<dim3((EE / 256) * GG), dim3(256), 0, stream>>>(ei, cnt, slot);
    k_scan<<<dim3(GG), dim3(256), 0, stream>>>(cnt, rowptr, dinv);
    k_fill<<<dim3((EE / 256) * GG), dim3(256), 0, stream>>>(ei, rowptr, slot, dinv, edges);

    // 3. h1 = bf16(x) @ W1  (round-4 verified gemm1)
    k_gemm1<<<dim3(MTOT / 64), dim3(256), 0, stream>>>(x, w1t, h1b);

    // 4. FUSED conv1 aggregate+ReLU+LN + @W2 -> h2b (bf16, 16 nodes/block)
    //    (h2b != h1b: other blocks still gather h1b)
    k_agg_gemm<<<dim3((NN / 16) * GG), dim3(512), 0, stream>>>(
        h1b, rowptr, edges, dinv, b1, g1, be1, w2t, h2b);

    // 5. conv2 aggregate + bias + LN -> d_out (fp32): 16 nodes/block
    k_agg<DOUT, false, float><<<dim3((NN / 16) * GG), dim3(256), 0, stream>>>(
        h2b, rowptr, edges, dinv, b2, g2, be2, out);
}